// Round 1
// baseline (248.707 us; speedup 1.0000x reference)
//
#include <hip/hip_runtime.h>
#include <hip/hip_cooperative_groups.h>
#include <math.h>

namespace cg = cooperative_groups;

// Problem constants
#define N_IMG 16
#define C_CH 3
#define H_DIM 512
#define W_DIM 512
#define HW (H_DIM * W_DIM)              // 262144
#define KS 7
#define PAD 3

// Fused-kernel tiling: 64x64 output tile per block.
// LDS tile now spans 72 columns (gx = bx*64-4 .. bx*64+67) so the global
// x-origin is 16B-aligned -> float4 staging on interior tiles.
#define TS 64
#define TROWS 70                        // 64 + 2*3 halo rows
#define TCOLS 72                        // 64 + 8 cols (aligned halo)
#define TSTRIDE 72                      // LDS row stride (floats)
#define TPB 256
#define TILES_PER_IMG ((H_DIM / TS) * (W_DIM / TS))   // 64
#define NBLOCKS (N_IMG * TILES_PER_IMG)               // 1024

// ws layout: three float arrays of per-block partials (no atomics anywhere)
//   pr  [NBLOCKS] : sum of residual over the block's interior pixels
//   pr2 [NBLOCKS] : sum of residual^2
//   pc  [NBLOCKS] : sum of pix_var * residual

// ---------------------------------------------------------------------------
// Single cooperative kernel:
//   phase 1: residual tile (reflect halo) -> LDS, 7x7 local unbiased variance
//            via ring-buffer row-sum sliding window, per-block partials -> ws
//   grid.sync()
//   phase 2: block 0 reduces 16 images' partials (double), applies pvar^0.2,
//            writes the scalar.
// __launch_bounds__(256,4): 4 waves/EU -> 4 blocks/CU -> all 1024 blocks
// co-resident (LDS 20160 B x 4 = 80 KB <= 160 KB; VGPR capped at 128).
// ---------------------------------------------------------------------------
__global__ __launch_bounds__(TPB, 4) void k_all(const float* __restrict__ pred,
                                                const float* __restrict__ targ,
                                                float* __restrict__ pr,
                                                float* __restrict__ pr2,
                                                float* __restrict__ pc,
                                                float* __restrict__ out) {
    __shared__ float tile[TROWS * TSTRIDE];

    const int bid = blockIdx.x;
    const int n   = bid >> 6;              // 64 tiles per image
    const int t   = bid & 63;
    const int by  = t >> 3;                // 8 tiles per dim
    const int bx  = t & 7;
    const int tid = threadIdx.x;

    const float* p0 = pred + (size_t)n * C_CH * HW;
    const float* p1 = p0 + HW;
    const float* p2 = p1 + HW;
    const float* q0 = targ + (size_t)n * C_CH * HW;
    const float* q1 = q0 + HW;
    const float* q2 = q1 + HW;

    const int y0 = by * TS - PAD;          // first halo row (gy of tile row 0)
    const int xa = bx * TS - 4;            // first halo col (gx of tile col 0), 16B-aligned

    if (by >= 1 && by <= 6 && bx >= 1 && bx <= 6) {
        // --- fast path (interior tile, no reflect): 70 rows x 18 float4 groups ---
        // rows y0..y0+69 in [61,450], cols xa..xa+71 in [60,451] -> always in-bounds
#pragma unroll
        for (int it = 0; it < 5; ++it) {
            const int i = tid + it * TPB;
            if (i < TROWS * 18) {
                const int r = i / 18;
                const int g = i - r * 18;
                const int goff = (y0 + r) * W_DIM + xa + g * 4;   // 16B-aligned
                const float4 a0 = *(const float4*)(p0 + goff);
                const float4 a1 = *(const float4*)(p1 + goff);
                const float4 a2 = *(const float4*)(p2 + goff);
                const float4 b0 = *(const float4*)(q0 + goff);
                const float4 b1 = *(const float4*)(q1 + goff);
                const float4 b2 = *(const float4*)(q2 + goff);
                float4 res;
                res.x = fabsf(b0.x - a0.x) + fabsf(b1.x - a1.x) + fabsf(b2.x - a2.x);
                res.y = fabsf(b0.y - a0.y) + fabsf(b1.y - a1.y) + fabsf(b2.y - a2.y);
                res.z = fabsf(b0.z - a0.z) + fabsf(b1.z - a1.z) + fabsf(b2.z - a2.z);
                res.w = fabsf(b0.w - a0.w) + fabsf(b1.w - a1.w) + fabsf(b2.w - a2.w);
                *(float4*)&tile[r * TSTRIDE + g * 4] = res;
            }
        }
    } else {
        // --- edge path (reflect): 70*72 = 5040 = 19*256 + 176 scalar pixels ---
#pragma unroll 4
        for (int it = 0; it < 20; ++it) {
            const int i = tid + it * TPB;
            if (i < TROWS * TCOLS) {
                const int ly = i / TCOLS;
                const int lx = i - ly * TCOLS;
                int gy = y0 + ly;
                int gx = xa + lx;
                gy = (gy < 0) ? -gy : ((gy >= H_DIM) ? (2 * H_DIM - 2 - gy) : gy);
                gx = (gx < 0) ? -gx : ((gx >= W_DIM) ? (2 * W_DIM - 2 - gx) : gx);
                const int off = gy * W_DIM + gx;
                tile[ly * TSTRIDE + lx] = fabsf(q0[off] - p0[off])
                                        + fabsf(q1[off] - p1[off])
                                        + fabsf(q2[off] - p2[off]);
            }
        }
    }
    __syncthreads();

    // --- 16 vertically-adjacent output pixels per thread ---
    // output col tx maps to LDS cols tx+1 .. tx+7 (center tx+4)
    const int tx  = tid & 63;              // output column 0..63
    const int ty0 = (tid >> 6) << 4;       // output rows ty0..ty0+15

    // ring buffer of per-row horizontal sums over the 7-wide window
    float rS[KS], rSS[KS];
    float S = 0.f, SS = 0.f;
#pragma unroll
    for (int dy = 0; dy < KS; ++dy) {
        float s = 0.f, ss = 0.f;
#pragma unroll
        for (int j = 0; j < KS; ++j) {
            const float v = tile[(ty0 + dy) * TSTRIDE + tx + 1 + j];
            s  += v;
            ss += v * v;
        }
        rS[dy] = s; rSS[dy] = ss;
        S += s; SS += ss;
    }

    float acc_r = 0.f, acc_r2 = 0.f, acc_c = 0.f;

#pragma unroll
    for (int k = 0; k < 16; ++k) {
        if (k > 0) {
            // slide down one row: add row ty0+6+k, drop oldest ring slot
            float s = 0.f, ss = 0.f;
#pragma unroll
            for (int j = 0; j < KS; ++j) {
                const float v = tile[(ty0 + 6 + k) * TSTRIDE + tx + 1 + j];
                s  += v;
                ss += v * v;
            }
            const int slot = (k - 1) % KS;   // compile-time after unroll
            S  += s  - rS[slot];
            SS += ss - rSS[slot];
            rS[slot] = s; rSS[slot] = ss;
        }
        const float pix_var = (SS - S * S * (1.0f / 49.0f)) * (1.0f / 48.0f);
        const float center  = tile[(ty0 + 3 + k) * TSTRIDE + tx + 4];

        acc_r  += center;
        acc_r2 += center * center;
        acc_c  += pix_var * center;
    }

    // --- block reduce 3 floats (wave shuffle -> LDS -> thread 0) ---
#pragma unroll
    for (int off = 32; off > 0; off >>= 1) {
        acc_r  += __shfl_down(acc_r,  off);
        acc_r2 += __shfl_down(acc_r2, off);
        acc_c  += __shfl_down(acc_c,  off);
    }
    __shared__ float sh_r[4], sh_r2[4], sh_c[4];
    const int lane = tid & 63;
    const int wave = tid >> 6;
    if (lane == 0) { sh_r[wave] = acc_r; sh_r2[wave] = acc_r2; sh_c[wave] = acc_c; }
    __syncthreads();
    if (tid == 0) {
        pr [bid] = sh_r [0] + sh_r [1] + sh_r [2] + sh_r [3];
        pr2[bid] = sh_r2[0] + sh_r2[1] + sh_r2[2] + sh_r2[3];
        pc [bid] = sh_c [0] + sh_c [1] + sh_c [2] + sh_c [3];
    }

    // --- phase 2: grid-wide finalize in block 0 ---
    cg::this_grid().sync();

    if (bid == 0) {
        double v = 0.0;
        if (tid < N_IMG) {
            double R = 0.0, R2 = 0.0, Cs = 0.0;
#pragma unroll 8
            for (int i = 0; i < TILES_PER_IMG; ++i) {
                const int idx = tid * TILES_PER_IMG + i;
                R  += (double)pr[idx];
                R2 += (double)pr2[idx];
                Cs += (double)pc[idx];
            }
            const double pvar = (R2 - R * R / (double)HW) / (double)(HW - 1);
            v = pow(pvar, 0.2) * Cs;
        }
        if (tid < 64) {
#pragma unroll
            for (int off = 8; off > 0; off >>= 1) v += __shfl_down(v, off);
            if (tid == 0) out[0] = (float)(v / ((double)N_IMG * C_CH * HW));
        }
    }
}

extern "C" void kernel_launch(void* const* d_in, const int* in_sizes, int n_in,
                              void* d_out, int out_size, void* d_ws, size_t ws_size,
                              hipStream_t stream) {
    const float* pred = (const float*)d_in[0];
    const float* targ = (const float*)d_in[1];

    float* pr  = (float*)d_ws;
    float* pr2 = pr  + NBLOCKS;
    float* pc  = pr2 + NBLOCKS;
    float* out = (float*)d_out;

    void* args[] = {(void*)&pred, (void*)&targ, (void*)&pr,
                    (void*)&pr2, (void*)&pc, (void*)&out};
    hipLaunchCooperativeKernel((const void*)k_all, dim3(NBLOCKS), dim3(TPB),
                               args, 0, stream);
}

// Round 2
// 131.262 us; speedup vs baseline: 1.8947x; 1.8947x over previous
//
#include <hip/hip_runtime.h>
#include <math.h>

// Problem constants
#define N_IMG 16
#define C_CH 3
#define H_DIM 512
#define W_DIM 512
#define HW (H_DIM * W_DIM)              // 262144
#define KS 7
#define PAD 3

// Tiling: 64 wide x 32 tall output tile per block -> 2048 blocks,
// 8 blocks/CU (32 waves/CU, 100% occupancy target).
// LDS tile spans 72 cols (gx = bx*64-4 .. bx*64+67): 16B-aligned x-origin
// so interior column-groups stage as float4.
#define TSX 64
#define TSY 32
#define TROWS (TSY + 2 * PAD)           // 38
#define TCOLS 72
#define TSTRIDE 72
#define TPB 256
#define NGROUPS (TROWS * 18)            // 684 float4-groups per tile
#define TILES_PER_IMG ((H_DIM / TSY) * (W_DIM / TSX))   // 128
#define NBLOCKS (N_IMG * TILES_PER_IMG)                 // 2048

// ws layout: three float arrays of per-block partials (no atomics anywhere)
//   pr  [NBLOCKS] : sum of residual over the block's interior pixels
//   pr2 [NBLOCKS] : sum of residual^2
//   pc  [NBLOCKS] : sum of pix_var * residual

__device__ __forceinline__ int reflect_y(int gy) {
    return (gy < 0) ? -gy : ((gy >= H_DIM) ? (2 * H_DIM - 2 - gy) : gy);
}
__device__ __forceinline__ int reflect_x(int gx) {
    return (gx < 0) ? -gx : ((gx >= W_DIM) ? (2 * W_DIM - 2 - gx) : gx);
}

// ---------------------------------------------------------------------------
// Fused kernel: residual (recomputed with reflect halo from pred/target) into
// LDS, 7x7 local unbiased variance via ring-buffer row-sum sliding window
// (8 px/thread), per-block partials -> ws.
// ---------------------------------------------------------------------------
__global__ __launch_bounds__(TPB, 8) void k_fused(const float* __restrict__ pred,
                                                  const float* __restrict__ targ,
                                                  float* __restrict__ pr,
                                                  float* __restrict__ pr2,
                                                  float* __restrict__ pc) {
    __shared__ float tile[TROWS * TSTRIDE];

    const int bid = blockIdx.x;
    const int n   = bid >> 7;              // 128 tiles per image
    const int t   = bid & 127;
    const int by  = t >> 3;                // 16 tiles vertically
    const int bx  = t & 7;                 // 8 tiles horizontally
    const int tid = threadIdx.x;

    const float* p0 = pred + (size_t)n * C_CH * HW;
    const float* p1 = p0 + HW;
    const float* p2 = p1 + HW;
    const float* q0 = targ + (size_t)n * C_CH * HW;
    const float* q1 = q0 + HW;
    const float* q2 = q1 + HW;

    const int y0 = by * TSY - PAD;         // first halo row (gy of tile row 0)
    const int xa = bx * TSX - 4;           // first halo col, 16B-aligned

    // --- staging: 38 rows x 18 float4-groups; row reflect is free (whole
    // row remaps), only groups crossing the x-border go scalar (bx 0/7 only)
#pragma unroll
    for (int it = 0; it < 3; ++it) {
        const int i = tid + it * TPB;
        if (i < NGROUPS) {
            const int r  = i / 18;
            const int g  = i - r * 18;
            const int gy = reflect_y(y0 + r);
            const int gx0 = xa + 4 * g;
            if (gx0 >= 0 && gx0 <= (W_DIM - 4)) {
                const int goff = gy * W_DIM + gx0;          // 16B-aligned
                const float4 a0 = *(const float4*)(p0 + goff);
                const float4 a1 = *(const float4*)(p1 + goff);
                const float4 a2 = *(const float4*)(p2 + goff);
                const float4 b0 = *(const float4*)(q0 + goff);
                const float4 b1 = *(const float4*)(q1 + goff);
                const float4 b2 = *(const float4*)(q2 + goff);
                float4 res;
                res.x = fabsf(b0.x - a0.x) + fabsf(b1.x - a1.x) + fabsf(b2.x - a2.x);
                res.y = fabsf(b0.y - a0.y) + fabsf(b1.y - a1.y) + fabsf(b2.y - a2.y);
                res.z = fabsf(b0.z - a0.z) + fabsf(b1.z - a1.z) + fabsf(b2.z - a2.z);
                res.w = fabsf(b0.w - a0.w) + fabsf(b1.w - a1.w) + fabsf(b2.w - a2.w);
                *(float4*)&tile[r * TSTRIDE + g * 4] = res;
            } else {
#pragma unroll
                for (int j = 0; j < 4; ++j) {
                    const int gx = reflect_x(gx0 + j);
                    const int off = gy * W_DIM + gx;
                    tile[r * TSTRIDE + g * 4 + j] = fabsf(q0[off] - p0[off])
                                                  + fabsf(q1[off] - p1[off])
                                                  + fabsf(q2[off] - p2[off]);
                }
            }
        }
    }
    __syncthreads();

    // --- 8 vertically-adjacent output pixels per thread ---
    // output col tx maps to LDS cols tx+1 .. tx+7 (center tx+4)
    const int tx  = tid & 63;              // output column 0..63
    const int ty0 = (tid >> 6) << 3;       // output rows ty0..ty0+7

    // ring buffer of per-row horizontal sums over the 7-wide window
    float rS[KS], rSS[KS];
    float S = 0.f, SS = 0.f;
#pragma unroll
    for (int dy = 0; dy < KS; ++dy) {
        float s = 0.f, ss = 0.f;
#pragma unroll
        for (int j = 0; j < KS; ++j) {
            const float v = tile[(ty0 + dy) * TSTRIDE + tx + 1 + j];
            s  += v;
            ss += v * v;
        }
        rS[dy] = s; rSS[dy] = ss;
        S += s; SS += ss;
    }

    float acc_r = 0.f, acc_r2 = 0.f, acc_c = 0.f;

#pragma unroll
    for (int k = 0; k < 8; ++k) {
        if (k > 0) {
            // slide down one row: add row ty0+6+k, drop oldest ring slot
            float s = 0.f, ss = 0.f;
#pragma unroll
            for (int j = 0; j < KS; ++j) {
                const float v = tile[(ty0 + 6 + k) * TSTRIDE + tx + 1 + j];
                s  += v;
                ss += v * v;
            }
            const int slot = k - 1;          // compile-time after unroll
            S  += s  - rS[slot];
            SS += ss - rSS[slot];
            rS[slot] = s; rSS[slot] = ss;
        }
        const float pix_var = (SS - S * S * (1.0f / 49.0f)) * (1.0f / 48.0f);
        const float center  = tile[(ty0 + 3 + k) * TSTRIDE + tx + 4];

        acc_r  += center;
        acc_r2 += center * center;
        acc_c  += pix_var * center;
    }

    // --- block reduce 3 floats (wave shuffle -> LDS -> thread 0) ---
#pragma unroll
    for (int off = 32; off > 0; off >>= 1) {
        acc_r  += __shfl_down(acc_r,  off);
        acc_r2 += __shfl_down(acc_r2, off);
        acc_c  += __shfl_down(acc_c,  off);
    }
    __shared__ float sh_r[4], sh_r2[4], sh_c[4];
    const int lane = tid & 63;
    const int wave = tid >> 6;
    if (lane == 0) { sh_r[wave] = acc_r; sh_r2[wave] = acc_r2; sh_c[wave] = acc_c; }
    __syncthreads();
    if (tid == 0) {
        pr [bid] = sh_r [0] + sh_r [1] + sh_r [2] + sh_r [3];
        pr2[bid] = sh_r2[0] + sh_r2[1] + sh_r2[2] + sh_r2[3];
        pc [bid] = sh_c [0] + sh_c [1] + sh_c [2] + sh_c [3];
    }
}

// ---------------------------------------------------------------------------
// Finalize: wave w reduces image w's 128 partials in double; lane 0 applies
// pw_n = pvar^0.2; thread 0 sums the 16 images and writes the scalar.
// ---------------------------------------------------------------------------
__global__ void k_final(const float* __restrict__ pr,
                        const float* __restrict__ pr2,
                        const float* __restrict__ pc,
                        float* __restrict__ out) {
    __shared__ double sh[N_IMG];
    const int tid  = threadIdx.x;       // 1024 threads = 16 waves
    const int w    = tid >> 6;          // image index
    const int lane = tid & 63;

    const int i0 = w * TILES_PER_IMG + lane;
    double R  = (double)pr [i0] + (double)pr [i0 + 64];
    double R2 = (double)pr2[i0] + (double)pr2[i0 + 64];
    double Cs = (double)pc [i0] + (double)pc [i0 + 64];
#pragma unroll
    for (int off = 32; off > 0; off >>= 1) {
        R  += __shfl_down(R,  off);
        R2 += __shfl_down(R2, off);
        Cs += __shfl_down(Cs, off);
    }
    if (lane == 0) {
        const double pvar = (R2 - R * R / (double)HW) / (double)(HW - 1);
        sh[w] = pow(pvar, 0.2) * Cs;
    }
    __syncthreads();
    if (tid == 0) {
        double s = 0.0;
        for (int i = 0; i < N_IMG; ++i) s += sh[i];
        out[0] = (float)(s / ((double)N_IMG * C_CH * HW));
    }
}

extern "C" void kernel_launch(void* const* d_in, const int* in_sizes, int n_in,
                              void* d_out, int out_size, void* d_ws, size_t ws_size,
                              hipStream_t stream) {
    const float* pred = (const float*)d_in[0];
    const float* targ = (const float*)d_in[1];

    float* pr  = (float*)d_ws;
    float* pr2 = pr  + NBLOCKS;
    float* pc  = pr2 + NBLOCKS;
    float* out = (float*)d_out;

    k_fused<<<NBLOCKS, TPB, 0, stream>>>(pred, targ, pr, pr2, pc);
    k_final<<<1, 1024, 0, stream>>>(pr, pr2, pc, out);
}